// Round 13
// baseline (493.961 us; speedup 1.0000x reference)
//
#include <hip/hip_runtime.h>
#include <hip/hip_bf16.h>
#include <math.h>

// Semantic predictor: wave-local bf16-MFMA transformer + fused MFMA head.
// Round 13: r12 winner + __launch_bounds__(512,8). Register need dropped to 40
// VGPR (dot2 QK, no xL/xH carry, sequential fc1) so the 64-VGPR cap no longer
// spills, and 4 blocks x 40960 B = exactly 160 KiB LDS -> 32 waves/CU.

typedef __attribute__((ext_vector_type(8))) short s16x8;
typedef __attribute__((ext_vector_type(4))) float f32x4;

#define ATTN_SCALE 0.35355339059327373f
#define WSLICE 640   // wave LDS slice stride in shorts (16 rows x 40)

__device__ __forceinline__ unsigned short bfc(float x) {
  __hip_bfloat16 h = __float2bfloat16(x);
  return __builtin_bit_cast(unsigned short, h);
}
// pack 2 f32 -> 2 bf16 in one u32 (lo -> bits[15:0])
__device__ __forceinline__ unsigned pk2(float lo, float hi) {
  float2 f; f.x = lo; f.y = hi;
  union { __hip_bfloat162 h; unsigned u; } cv;
  cv.h = __float22bfloat162_rn(f);
  return cv.u;
}
__device__ __forceinline__ float fbc(unsigned short u) {
  union { unsigned v; float f; } w; w.v = ((unsigned)u) << 16;
  return w.f;
}
__device__ __forceinline__ float f_lo(unsigned u) {
  union { unsigned v; float f; } w; w.v = u << 16; return w.f;
}
__device__ __forceinline__ float f_hi(unsigned u) {
  union { unsigned v; float f; } w; w.v = u & 0xffff0000u; return w.f;
}
__device__ __forceinline__ float elu_f(float x) { return x > 0.f ? x : __expf(x) - 1.f; }

// d += dot2(bf16x2 a, bf16x2 b): HW packed dot if available, else unpack+fma
#if __has_builtin(__builtin_amdgcn_fdot2_f32_bf16)
typedef __attribute__((ext_vector_type(2))) __bf16 bf16x2;
__device__ __forceinline__ float dot2bf(unsigned a, unsigned b, float c) {
  return __builtin_amdgcn_fdot2_f32_bf16(__builtin_bit_cast(bf16x2, a),
                                         __builtin_bit_cast(bf16x2, b), c, false);
}
#else
__device__ __forceinline__ float dot2bf(unsigned a, unsigned b, float c) {
  return c + f_lo(a) * f_lo(b) + f_hi(a) * f_hi(b);
}
#endif

// 16-lane DPP butterfly sum (xor1, xor2, half-mirror, mirror) — zero DS ops
__device__ __forceinline__ float row16_sum(float x) {
  int v;
  v = __builtin_amdgcn_update_dpp(0, __builtin_bit_cast(int, x), 0xB1,  0xF, 0xF, true);
  x += __builtin_bit_cast(float, v);
  v = __builtin_amdgcn_update_dpp(0, __builtin_bit_cast(int, x), 0x4E,  0xF, 0xF, true);
  x += __builtin_bit_cast(float, v);
  v = __builtin_amdgcn_update_dpp(0, __builtin_bit_cast(int, x), 0x141, 0xF, 0xF, true);
  x += __builtin_bit_cast(float, v);
  v = __builtin_amdgcn_update_dpp(0, __builtin_bit_cast(int, x), 0x140, 0xF, 0xF, true);
  x += __builtin_bit_cast(float, v);
  return x;
}

__device__ __forceinline__ f32x4 mfma16(s16x8 a, s16x8 b, f32x4 c) {
  return __builtin_amdgcn_mfma_f32_16x16x32_bf16(a, b, c, 0, 0, 0);
}
// B fragment from bf16 WT[n][32]: n = nt*16 + c, k = gq*8..+8
__device__ __forceinline__ s16x8 ldB32(const unsigned short* __restrict__ wt, int nt, int c, int gq) {
  return *(const s16x8*)(wt + (nt * 16 + c) * 32 + (gq << 3));
}

// ---------------- weight prep: f32 -> bf16, transposed (159,744 B) ----------------
// per-layer slots: 0=Wq, 1=Wk, 2=W_vo(=Wv@Wo, fp32-fused), 3=unused, 4=W1, 5=W2
__global__ void prep_kernel(const float* __restrict__ wq, const float* __restrict__ wk,
                            const float* __restrict__ wv, const float* __restrict__ wo,
                            const float* __restrict__ w1, const float* __restrict__ w2,
                            const float* __restrict__ fc1w, const float* __restrict__ fc2w,
                            unsigned short* __restrict__ ws)
{
  int i = blockIdx.x * blockDim.x + threadIdx.x;
  int stride = gridDim.x * blockDim.x;
  // transformer mats: [l][mat][n][k], INTERLEAVED n: tile nt row nn -> orig col 2*nn+nt
  for (int t = i; t < 24576; t += stride) {
    int lm = t >> 10;
    int l = lm / 6, m = lm - l * 6;
    int j = t & 1023, n = j >> 5, k = j & 31;
    int col = 2 * (n & 15) + (n >> 4);
    float val;
    if (m == 2) {            // W_vo[k][col] = sum_j Wv[k][j] * Wo[j][col] (fp32)
      float acc = 0.f;
#pragma unroll 8
      for (int jj = 0; jj < 32; ++jj)
        acc += wv[l * 1024 + k * 32 + jj] * wo[l * 1024 + jj * 32 + col];
      val = acc;
    } else if (m == 3) {
      val = 0.f;             // unused slot
    } else {
      const float* mp = (m == 0) ? wq : (m == 1) ? wk : (m == 4) ? w1 : w2;
      val = mp[l * 1024 + k * 32 + col];
    }
    ws[t] = bfc(val);
  }
  for (int t = i; t < 36864; t += stride) {       // WT1[n(192)][k(192)] (original order)
    int n = t / 192, k = t - n * 192;
    ws[24576 + t] = bfc(fc1w[k * 192 + n]);
  }
  for (int t = i; t < 18432; t += stride) {       // WT2[n(96)][k(192)]
    int n = t / 192, k = t - n * 192;
    ws[61440 + t] = bfc(fc2w[k * 96 + n]);
  }
}

// ---------------- main fused kernel ----------------
__global__ __launch_bounds__(512, 8)
void sem_main(const float* __restrict__ feat, const float* __restrict__ occ,
              const float* __restrict__ tokw, const float* __restrict__ tokb,
              const float* __restrict__ ln1g, const float* __restrict__ ln1b,
              const float* __restrict__ fb1,  const float* __restrict__ fb2,
              const float* __restrict__ ln2g, const float* __restrict__ ln2b,
              const float* __restrict__ fc1b, const float* __restrict__ fc2b,
              const float* __restrict__ fc3w, const float* __restrict__ fc3b,
              const unsigned short* __restrict__ wsq,   // [l][6][32][32] interleaved-n
              const unsigned short* __restrict__ wt1,   // [192][192]
              const unsigned short* __restrict__ wt2,   // [96][192]
              float* __restrict__ outp, int ntot)
{
  // 40960 B total. B0 @0, B1 @5120, B2 @10240, B3 @15360 (8 slices x 640 each).
  // Head aliases: e1 @5120, e2 @8320, WTL @10240 (live only when B1/B2 dead).
  __shared__ unsigned short SH[20480];

  const int tid  = threadIdx.x;
  const int lane = tid & 63;
  const int wid  = tid >> 6;
  const int c    = lane & 15;
  const int gq   = lane >> 4;
  const int n0b  = blockIdx.x * 16;
  const int n0   = n0b + wid * 2;

  unsigned short* B0 = SH          + wid * WSLICE;
  unsigned short* B1 = SH +  5120 + wid * WSLICE;
  unsigned short* B2 = SH + 10240 + wid * WSLICE;
  unsigned short* B3 = SH + 15360 + wid * WSLICE;
  unsigned short* e1  = SH + 5120;
  unsigned short* e2  = SH + 8320;
  unsigned short* WTL = SH + 10240;

  // ---- stage wtok -> WTL (interleaved-n, k>=21 zero) ----
  for (int t = tid; t < 1024; t += 512) {
    int n = t >> 5, k = t & 31;
    int col = 2 * (n & 15) + (n >> 4);
    WTL[t] = (k < 21) ? bfc(tokw[k * 32 + col]) : (unsigned short)0;
  }

  // ---- additive attention masks in registers (per this lane's attn sample) ----
  float addm6[6];
  {
    int s_att = (lane >= 24 && lane < 48) ? 1 : 0;
    int nm = n0 + s_att;
    float msk6[6];
    if (nm < ntot) {
      float vr[6], mc[6];
#pragma unroll
      for (int u = 0; u < 6; ++u) vr[u] = feat[(size_t)(nm * 6 + u) * 48 + 47];
      float s0 = vr[0]+vr[1]+vr[2]+vr[3]+vr[4]+vr[5];
#pragma unroll
      for (int u = 0; u < 6; ++u) { vr[u] = (s0 == 0.f) ? 1.f : vr[u]; mc[u] = vr[u]; }
#pragma unroll
      for (int u = 0; u < 6; ++u) vr[u] *= occ[nm * 6 + u];
      float s2 = vr[0]+vr[1]+vr[2]+vr[3]+vr[4]+vr[5];
#pragma unroll
      for (int u = 0; u < 6; ++u) msk6[u] = ((s2 == 0.f) ? 1.f : vr[u]) * mc[u];
    } else {
#pragma unroll
      for (int u = 0; u < 6; ++u) msk6[u] = 1.f;
    }
#pragma unroll
    for (int u = 0; u < 6; ++u) addm6[u] = (msk6[u] == 0.f) ? -INFINITY : 0.f;
  }

  // ---- stage feat -> bf16 A-tile in B1 (packed b32 writes) ----
  if (lane < 24) {
    int r12 = lane >> 1, half = lane & 1;
    int s = r12 / 6, v = r12 - s * 6;
    int n = n0 + s;
    int row = s * 8 + v;
    unsigned* dst = (unsigned*)(B1 + row * 40) + half * 8;
    if (n < ntot) {
      const float* fb = feat + (size_t)(n * 6 + v) * 48;
      if (half == 0) {
        float4 fA = *(const float4*)(fb + 24);
        float4 fB = *(const float4*)(fb + 28);
        float4 fC = *(const float4*)(fb + 32);
        float4 fD = *(const float4*)(fb + 36);
        dst[0] = pk2(fb[47], fA.x); dst[1] = pk2(fA.y, fA.z);
        dst[2] = pk2(fA.w, fB.x);  dst[3] = pk2(fB.y, fB.z);
        dst[4] = pk2(fB.w, fC.x);  dst[5] = pk2(fC.y, fC.z);
        dst[6] = pk2(fC.w, fD.x);  dst[7] = pk2(fD.y, fD.z);
      } else {
        float4 fE = *(const float4*)(fb + 40);
        dst[0] = pk2(fb[39], fE.x); dst[1] = pk2(fE.y, fE.z);
        dst[2] = pk2(fE.w, 0.f);
        dst[3] = 0u; dst[4] = 0u; dst[5] = 0u; dst[6] = 0u; dst[7] = 0u;
      }
    } else {
#pragma unroll
      for (int j = 0; j < 8; ++j) dst[j] = 0u;
    }
  } else if (lane < 40) {
    int pr = (lane - 24) >> 2, q = (lane - 24) & 3;
    int row = (pr >> 1) * 8 + 6 + (pr & 1);
    unsigned* dst = (unsigned*)(B1 + row * 40) + q * 4;
    dst[0] = 0u; dst[1] = 0u; dst[2] = 0u; dst[3] = 0u;
  }
  __syncthreads();   // WTL(wtok) + B1 A-tiles ready

  // residual pairs for rows gq*4+i, cols (2c, 2c+1), carried in registers
  float resL[4], resH[4];

  // ---- token embedding: MFMA pair + ELU, paired-col store -> B0 ----
  {
    s16x8 a = *(const s16x8*)(B1 + c * 40 + (gq << 3));
    f32x4 c0 = {0.f,0.f,0.f,0.f}, c1 = c0;
    c0 = mfma16(a, ldB32(WTL, 0, c, gq), c0);
    c1 = mfma16(a, ldB32(WTL, 1, c, gq), c1);
    float2 tb = *(const float2*)(tokb + 2 * c);
#pragma unroll
    for (int i = 0; i < 4; ++i) {
      int row = gq * 4 + i;
      float e0 = elu_f(c0[i] + tb.x), e1v = elu_f(c1[i] + tb.y);
      resL[i] = e0; resH[i] = e1v;
      *(unsigned*)(B0 + row * 40 + 2 * c) = pk2(e0, e1v);
    }
  }
  __syncthreads();   // all waves done reading WTL before layer-0 K/V overwrite it

  // ---- transformer layers ----
  for (int l = 0; l < 4; ++l) {
    const unsigned short* wl = wsq + l * 6144;

    // QKV': Q -> B1, K -> B2, V~ = T @ (Wv@Wo) -> B3
    {
      s16x8 a = *(const s16x8*)(B0 + c * 40 + (gq << 3));
      f32x4 cq0 = {0.f,0.f,0.f,0.f}, cq1 = cq0, ck0 = cq0, ck1 = cq0, cv0 = cq0, cv1 = cq0;
      cq0 = mfma16(a, ldB32(wl,        0, c, gq), cq0);
      cq1 = mfma16(a, ldB32(wl,        1, c, gq), cq1);
      ck0 = mfma16(a, ldB32(wl + 1024, 0, c, gq), ck0);
      ck1 = mfma16(a, ldB32(wl + 1024, 1, c, gq), ck1);
      cv0 = mfma16(a, ldB32(wl + 2048, 0, c, gq), cv0);
      cv1 = mfma16(a, ldB32(wl + 2048, 1, c, gq), cv1);
#pragma unroll
      for (int i = 0; i < 4; ++i) {
        int ro = (gq * 4 + i) * 40 + 2 * c;
        *(unsigned*)(B1 + ro) = pk2(cq0[i], cq1[i]);
        *(unsigned*)(B2 + ro) = pk2(ck0[i], ck1[i]);
        *(unsigned*)(B3 + ro) = pk2(cv0[i], cv1[i]);
      }
    }
    __builtin_amdgcn_wave_barrier();

    // attention: 48 lane jobs (s,q,h); O' (includes @Wo) overwrites own Q-slot in B1
    if (lane < 48) {
      int s = lane / 24, t = lane - s * 24, q = t >> 2, h = t & 3;
      int row = s * 8 + q;
      uint4 qf = *(const uint4*)(B1 + row * 40 + h * 8);
      float p6[6];
#pragma unroll
      for (int u = 0; u < 6; ++u) {
        uint4 kf = *(const uint4*)(B2 + (s * 8 + u) * 40 + h * 8);
        float d = dot2bf(qf.x, kf.x, 0.f);
        d = dot2bf(qf.y, kf.y, d);
        d = dot2bf(qf.z, kf.z, d);
        d = dot2bf(qf.w, kf.w, d);
        p6[u] = fmaf(d, ATTN_SCALE, addm6[u]);
      }
      float mx = p6[0];
#pragma unroll
      for (int u = 1; u < 6; ++u) mx = fmaxf(mx, p6[u]);
      float sum = 0.f;
#pragma unroll
      for (int u = 0; u < 6; ++u) { float e = __expf(p6[u] - mx); p6[u] = e; sum += e; }
      float inv = 1.f / sum;
      float o[8];
#pragma unroll
      for (int i = 0; i < 8; ++i) o[i] = 0.f;
#pragma unroll
      for (int u = 0; u < 6; ++u) {
        s16x8 vf = *(const s16x8*)(B3 + (s * 8 + u) * 40 + h * 8);
        float pw = p6[u] * inv;
#pragma unroll
        for (int i = 0; i < 8; ++i) o[i] += pw * fbc((unsigned short)vf[i]);
      }
      unsigned* op = (unsigned*)(B1 + row * 40 + h * 8);
      op[0] = pk2(o[0], o[1]); op[1] = pk2(o[2], o[3]);
      op[2] = pk2(o[4], o[5]); op[3] = pk2(o[6], o[7]);
    }
    __builtin_amdgcn_wave_barrier();

    // X = LN1(O'[B1] + res[regs]) -> B2   (pure VALU/LDS, no MFMA)
    {
      float2 g2 = *(const float2*)(ln1g + l*32 + 2*c);
      float2 b2 = *(const float2*)(ln1b + l*32 + 2*c);
#pragma unroll
      for (int i = 0; i < 4; ++i) {
        int row = gq * 4 + i;
        unsigned opk = *(const unsigned*)(B1 + row * 40 + 2 * c);
        float x0 = f_lo(opk) + resL[i];
        float x1 = f_hi(opk) + resH[i];
        float s  = row16_sum(x0 + x1);
        float ss = row16_sum(x0 * x0 + x1 * x1);
        float mean = s * 0.03125f;
        float var  = fmaxf(ss * 0.03125f - mean * mean, 0.f);
        float rr   = rsqrtf(var + 1e-6f);
        *(unsigned*)(B2 + row * 40 + 2 * c) =
            pk2((x0 - mean) * rr * g2.x + b2.x, (x1 - mean) * rr * g2.y + b2.y);
      }
    }
    __builtin_amdgcn_wave_barrier();

    // H = relu(X @ W1 + b1):  A=B2 -> B3
    {
      s16x8 a = *(const s16x8*)(B2 + c * 40 + (gq << 3));
      f32x4 c0 = {0.f,0.f,0.f,0.f}, c1 = c0;
      c0 = mfma16(a, ldB32(wl + 4096, 0, c, gq), c0);
      c1 = mfma16(a, ldB32(wl + 4096, 1, c, gq), c1);
      float2 bi = *(const float2*)(fb1 + l*32 + 2*c);
#pragma unroll
      for (int i = 0; i < 4; ++i) {
        int row = gq * 4 + i;
        *(unsigned*)(B3 + row * 40 + 2 * c) =
            pk2(fmaxf(c0[i] + bi.x, 0.f), fmaxf(c1[i] + bi.y, 0.f));
      }
    }
    __builtin_amdgcn_wave_barrier();

    // T' = LN2(H @ W2 + b2 + X[B2]) -> B0, residual regs updated
    {
      s16x8 a = *(const s16x8*)(B3 + c * 40 + (gq << 3));
      f32x4 c0 = {0.f,0.f,0.f,0.f}, c1 = c0;
      c0 = mfma16(a, ldB32(wl + 5120, 0, c, gq), c0);
      c1 = mfma16(a, ldB32(wl + 5120, 1, c, gq), c1);
      float2 g2 = *(const float2*)(ln2g + l*32 + 2*c);
      float2 b2 = *(const float2*)(ln2b + l*32 + 2*c);
      float2 bi = *(const float2*)(fb2 + l*32 + 2*c);
#pragma unroll
      for (int i = 0; i < 4; ++i) {
        int row = gq * 4 + i;
        unsigned xp = *(const unsigned*)(B2 + row * 40 + 2 * c);
        float x0 = c0[i] + bi.x + f_lo(xp);
        float x1 = c1[i] + bi.y + f_hi(xp);
        float s  = row16_sum(x0 + x1);
        float ss = row16_sum(x0 * x0 + x1 * x1);
        float mean = s * 0.03125f;
        float var  = fmaxf(ss * 0.03125f - mean * mean, 0.f);
        float rr   = rsqrtf(var + 1e-6f);
        float o0 = (x0 - mean) * rr * g2.x + b2.x;
        float o1 = (x1 - mean) * rr * g2.y + b2.y;
        resL[i] = o0; resH[i] = o1;
        *(unsigned*)(B0 + row * 40 + 2 * c) = pk2(o0, o1);
      }
    }
    __builtin_amdgcn_wave_barrier();
  }

  // ---- head: block = 16 samples = one M=16 tile ----
  __syncthreads();   // transformer done; B1/B2 regions dead -> alias e1/e2/WTL

  // stage wt3 -> WTL: WT3[n(32)][k(96)], n>=20 zero (original order)
  for (int t = tid; t < 3072; t += 512) {
    int n = t / 96, k = t - n * 96;
    WTL[t] = (n < 20) ? bfc(fc3w[k * 20 + n]) : (unsigned short)0;
  }

  // fc1: A-frag sample = c, k = (v=ck)*32.. ; 12 n-tiles over 8 waves
  // sequential store-then-compute to cap register pressure
  {
    s16x8 a6[6];
#pragma unroll
    for (int ck = 0; ck < 6; ++ck)
      a6[ck] = *(const s16x8*)(SH + (c >> 1) * WSLICE + ((c & 1) * 8 + ck) * 40 + (gq << 3));
    int nt = wid;
    f32x4 acc = {0.f,0.f,0.f,0.f};
#pragma unroll
    for (int ck = 0; ck < 6; ++ck)
      acc = mfma16(a6[ck], *(const s16x8*)(wt1 + (nt*16 + c) * 192 + ck*32 + (gq << 3)), acc);
    float bi = fc1b[nt * 16 + c];
#pragma unroll
    for (int i = 0; i < 4; ++i)
      e1[(gq * 4 + i) * 200 + nt * 16 + c] = bfc(elu_f(acc[i] + bi));
    if (wid < 4) {
      int nt2 = wid + 8;
      f32x4 acc2 = {0.f,0.f,0.f,0.f};
#pragma unroll
      for (int ck = 0; ck < 6; ++ck)
        acc2 = mfma16(a6[ck], *(const s16x8*)(wt1 + (nt2*16 + c) * 192 + ck*32 + (gq << 3)), acc2);
      float bi2 = fc1b[nt2 * 16 + c];
#pragma unroll
      for (int i = 0; i < 4; ++i)
        e1[(gq * 4 + i) * 200 + nt2 * 16 + c] = bfc(elu_f(acc2[i] + bi2));
    }
  }
  __syncthreads();

  // fc2: 6 n-tiles over waves 0..5
  if (wid < 6) {
    s16x8 h6[6];
#pragma unroll
    for (int ck = 0; ck < 6; ++ck)
      h6[ck] = *(const s16x8*)(e1 + c * 200 + ck * 32 + (gq << 3));
    int nt = wid;
    f32x4 acc = {0.f,0.f,0.f,0.f};
#pragma unroll
    for (int ck = 0; ck < 6; ++ck)
      acc = mfma16(h6[ck], *(const s16x8*)(wt2 + (nt*16 + c) * 192 + ck*32 + (gq << 3)), acc);
    float bi = fc2b[nt * 16 + c];
    int base = nt * 16 + c;
#pragma unroll
    for (int i = 0; i < 4; ++i)
      e2[(gq * 4 + i) * 104 + base] = bfc(elu_f(acc[i] + bi));
  }
  __syncthreads();

  // fc3: M=16 x N=20(pad32) x K=96 on waves 6,7 (3 MFMAs each)
  if (wid >= 6) {
    int nt = wid - 6;
    s16x8 a3[3];
#pragma unroll
    for (int ck = 0; ck < 3; ++ck)
      a3[ck] = *(const s16x8*)(e2 + c * 104 + ck * 32 + (gq << 3));
    f32x4 acc = {0.f,0.f,0.f,0.f};
#pragma unroll
    for (int ck = 0; ck < 3; ++ck)
      acc = mfma16(a3[ck], *(const s16x8*)(WTL + (nt*16 + c) * 96 + ck*32 + (gq << 3)), acc);
    int col = nt * 16 + c;
    if (col < 20) {
      float bi = fc3b[col];
#pragma unroll
      for (int i = 0; i < 4; ++i) {
        int n = n0b + gq * 4 + i;
        if (n < ntot) outp[(size_t)n * 20 + col] = fmaxf(acc[i] + bi, 0.f);
      }
    }
  }
}

extern "C" void kernel_launch(void* const* d_in, const int* in_sizes, int n_in,
                              void* d_out, int out_size, void* d_ws, size_t ws_size,
                              hipStream_t stream)
{
  const float* feat = (const float*)d_in[0];
  const float* occ  = (const float*)d_in[1];
  const float* tokw = (const float*)d_in[2];
  const float* tokb = (const float*)d_in[3];
  const float* wq   = (const float*)d_in[4];
  const float* wk   = (const float*)d_in[5];
  const float* wv   = (const float*)d_in[6];
  const float* wo   = (const float*)d_in[7];
  const float* ln1g = (const float*)d_in[8];
  const float* ln1b = (const float*)d_in[9];
  const float* fw1  = (const float*)d_in[10];
  const float* fb1  = (const float*)d_in[11];
  const float* fw2  = (const float*)d_in[12];
  const float* fb2  = (const float*)d_in[13];
  const float* ln2g = (const float*)d_in[14];
  const float* ln2b = (const float*)d_in[15];
  const float* fc1w = (const float*)d_in[16];
  const float* fc1b = (const float*)d_in[17];
  const float* fc2w = (const float*)d_in[18];
  const float* fc2b = (const float*)d_in[19];
  const float* fc3w = (const float*)d_in[20];
  const float* fc3b = (const float*)d_in[21];
  float* outp = (float*)d_out;

  unsigned short* ws = (unsigned short*)d_ws;
  const int ntot = in_sizes[0] / 288;

  hipLaunchKernelGGL(prep_kernel, dim3(128), dim3(256), 0, stream,
                     wq, wk, wv, wo, fw1, fw2, fc1w, fc2w, ws);

  const int grid = (ntot + 15) / 16;
  hipLaunchKernelGGL(sem_main, dim3(grid), dim3(512), 0, stream,
                     feat, occ, tokw, tokb, ln1g, ln1b, fb1, fb2, ln2g, ln2b,
                     fc1b, fc2b, fc3w, fc3b,
                     ws, ws + 24576, ws + 61440,
                     outp, ntot);
}

// Round 14
// 376.879 us; speedup vs baseline: 1.3107x; 1.3107x over previous
//
#include <hip/hip_runtime.h>
#include <hip/hip_bf16.h>
#include <math.h>

// Semantic predictor: wave-local bf16-MFMA transformer + fused MFMA head.
// Round 14: r12 occupancy point ((512,6), 3 blocks/CU, spill-free) + r10's
// verified fused attention+LN1 epilogue (quad-DPP over h-lanes). Layer = 4
// phases: QKV' -> attn+LN1 -> FFN1 -> LN2. No residual register carry
// (residual read from B0/B1 in LDS). W_vo = Wv@Wo fp32 fusion; dot2 QK.

typedef __attribute__((ext_vector_type(8))) short s16x8;
typedef __attribute__((ext_vector_type(4))) float f32x4;

#define ATTN_SCALE 0.35355339059327373f
#define WSLICE 640   // wave LDS slice stride in shorts (16 rows x 40)

__device__ __forceinline__ unsigned short bfc(float x) {
  __hip_bfloat16 h = __float2bfloat16(x);
  return __builtin_bit_cast(unsigned short, h);
}
// pack 2 f32 -> 2 bf16 in one u32 (lo -> bits[15:0])
__device__ __forceinline__ unsigned pk2(float lo, float hi) {
  float2 f; f.x = lo; f.y = hi;
  union { __hip_bfloat162 h; unsigned u; } cv;
  cv.h = __float22bfloat162_rn(f);
  return cv.u;
}
__device__ __forceinline__ float fbc(unsigned short u) {
  union { unsigned v; float f; } w; w.v = ((unsigned)u) << 16;
  return w.f;
}
__device__ __forceinline__ float f_lo(unsigned u) {
  union { unsigned v; float f; } w; w.v = u << 16; return w.f;
}
__device__ __forceinline__ float f_hi(unsigned u) {
  union { unsigned v; float f; } w; w.v = u & 0xffff0000u; return w.f;
}
__device__ __forceinline__ float elu_f(float x) { return x > 0.f ? x : __expf(x) - 1.f; }

// d += dot2(bf16x2 a, bf16x2 b): HW packed dot if available, else unpack+fma
#if __has_builtin(__builtin_amdgcn_fdot2_f32_bf16)
typedef __attribute__((ext_vector_type(2))) __bf16 bf16x2;
__device__ __forceinline__ float dot2bf(unsigned a, unsigned b, float c) {
  return __builtin_amdgcn_fdot2_f32_bf16(__builtin_bit_cast(bf16x2, a),
                                         __builtin_bit_cast(bf16x2, b), c, false);
}
#else
__device__ __forceinline__ float dot2bf(unsigned a, unsigned b, float c) {
  return c + f_lo(a) * f_lo(b) + f_hi(a) * f_hi(b);
}
#endif

// 16-lane DPP butterfly sum (xor1, xor2, half-mirror, mirror) — zero DS ops
__device__ __forceinline__ float row16_sum(float x) {
  int v;
  v = __builtin_amdgcn_update_dpp(0, __builtin_bit_cast(int, x), 0xB1,  0xF, 0xF, true);
  x += __builtin_bit_cast(float, v);
  v = __builtin_amdgcn_update_dpp(0, __builtin_bit_cast(int, x), 0x4E,  0xF, 0xF, true);
  x += __builtin_bit_cast(float, v);
  v = __builtin_amdgcn_update_dpp(0, __builtin_bit_cast(int, x), 0x141, 0xF, 0xF, true);
  x += __builtin_bit_cast(float, v);
  v = __builtin_amdgcn_update_dpp(0, __builtin_bit_cast(int, x), 0x140, 0xF, 0xF, true);
  x += __builtin_bit_cast(float, v);
  return x;
}
// 4-lane (quad) butterfly sum: quad_perm [1,0,3,2] then [2,3,0,1]
__device__ __forceinline__ float quad_sum(float x) {
  int v;
  v = __builtin_amdgcn_update_dpp(0, __builtin_bit_cast(int, x), 0xB1, 0xF, 0xF, true);
  x += __builtin_bit_cast(float, v);
  v = __builtin_amdgcn_update_dpp(0, __builtin_bit_cast(int, x), 0x4E, 0xF, 0xF, true);
  x += __builtin_bit_cast(float, v);
  return x;
}

__device__ __forceinline__ f32x4 mfma16(s16x8 a, s16x8 b, f32x4 c) {
  return __builtin_amdgcn_mfma_f32_16x16x32_bf16(a, b, c, 0, 0, 0);
}
// B fragment from bf16 WT[n][32]: n = nt*16 + c, k = gq*8..+8
__device__ __forceinline__ s16x8 ldB32(const unsigned short* __restrict__ wt, int nt, int c, int gq) {
  return *(const s16x8*)(wt + (nt * 16 + c) * 32 + (gq << 3));
}

// ---------------- weight prep: f32 -> bf16, transposed (159,744 B) ----------------
// per-layer slots: 0=Wq, 1=Wk, 2=W_vo(=Wv@Wo, fp32-fused), 3=unused, 4=W1, 5=W2
__global__ void prep_kernel(const float* __restrict__ wq, const float* __restrict__ wk,
                            const float* __restrict__ wv, const float* __restrict__ wo,
                            const float* __restrict__ w1, const float* __restrict__ w2,
                            const float* __restrict__ fc1w, const float* __restrict__ fc2w,
                            unsigned short* __restrict__ ws)
{
  int i = blockIdx.x * blockDim.x + threadIdx.x;
  int stride = gridDim.x * blockDim.x;
  // transformer mats: [l][mat][n][k], INTERLEAVED n: tile nt row nn -> orig col 2*nn+nt
  for (int t = i; t < 24576; t += stride) {
    int lm = t >> 10;
    int l = lm / 6, m = lm - l * 6;
    int j = t & 1023, n = j >> 5, k = j & 31;
    int col = 2 * (n & 15) + (n >> 4);
    float val;
    if (m == 2) {            // W_vo[k][col] = sum_j Wv[k][j] * Wo[j][col] (fp32)
      float acc = 0.f;
#pragma unroll 8
      for (int jj = 0; jj < 32; ++jj)
        acc += wv[l * 1024 + k * 32 + jj] * wo[l * 1024 + jj * 32 + col];
      val = acc;
    } else if (m == 3) {
      val = 0.f;             // unused slot
    } else {
      const float* mp = (m == 0) ? wq : (m == 1) ? wk : (m == 4) ? w1 : w2;
      val = mp[l * 1024 + k * 32 + col];
    }
    ws[t] = bfc(val);
  }
  for (int t = i; t < 36864; t += stride) {       // WT1[n(192)][k(192)] (original order)
    int n = t / 192, k = t - n * 192;
    ws[24576 + t] = bfc(fc1w[k * 192 + n]);
  }
  for (int t = i; t < 18432; t += stride) {       // WT2[n(96)][k(192)]
    int n = t / 192, k = t - n * 192;
    ws[61440 + t] = bfc(fc2w[k * 96 + n]);
  }
}

// ---------------- main fused kernel ----------------
__global__ __launch_bounds__(512, 6)
void sem_main(const float* __restrict__ feat, const float* __restrict__ occ,
              const float* __restrict__ tokw, const float* __restrict__ tokb,
              const float* __restrict__ ln1g, const float* __restrict__ ln1b,
              const float* __restrict__ fb1,  const float* __restrict__ fb2,
              const float* __restrict__ ln2g, const float* __restrict__ ln2b,
              const float* __restrict__ fc1b, const float* __restrict__ fc2b,
              const float* __restrict__ fc3w, const float* __restrict__ fc3b,
              const unsigned short* __restrict__ wsq,   // [l][6][32][32] interleaved-n
              const unsigned short* __restrict__ wt1,   // [192][192]
              const unsigned short* __restrict__ wt2,   // [96][192]
              float* __restrict__ outp, int ntot)
{
  // 40960 B total. B0 @0, B1 @5120, B2 @10240, B3 @15360 (8 slices x 640 each).
  // Head aliases: e1 @5120, e2 @8320, WTL @10240 (live only when B1/B2 dead).
  __shared__ unsigned short SH[20480];

  const int tid  = threadIdx.x;
  const int lane = tid & 63;
  const int wid  = tid >> 6;
  const int c    = lane & 15;
  const int gq   = lane >> 4;
  const int n0b  = blockIdx.x * 16;
  const int n0   = n0b + wid * 2;

  unsigned short* B0 = SH          + wid * WSLICE;
  unsigned short* B1 = SH +  5120 + wid * WSLICE;
  unsigned short* B2 = SH + 10240 + wid * WSLICE;
  unsigned short* B3 = SH + 15360 + wid * WSLICE;
  unsigned short* e1  = SH + 5120;
  unsigned short* e2  = SH + 8320;
  unsigned short* WTL = SH + 10240;

  // ---- stage wtok -> WTL (interleaved-n, k>=21 zero) ----
  for (int t = tid; t < 1024; t += 512) {
    int n = t >> 5, k = t & 31;
    int col = 2 * (n & 15) + (n >> 4);
    WTL[t] = (k < 21) ? bfc(tokw[k * 32 + col]) : (unsigned short)0;
  }

  // ---- additive attention masks in registers (per this lane's attn sample) ----
  float addm6[6];
  {
    int s_att = (lane >= 24 && lane < 48) ? 1 : 0;
    int nm = n0 + s_att;
    float msk6[6];
    if (nm < ntot) {
      float vr[6], mc[6];
#pragma unroll
      for (int u = 0; u < 6; ++u) vr[u] = feat[(size_t)(nm * 6 + u) * 48 + 47];
      float s0 = vr[0]+vr[1]+vr[2]+vr[3]+vr[4]+vr[5];
#pragma unroll
      for (int u = 0; u < 6; ++u) { vr[u] = (s0 == 0.f) ? 1.f : vr[u]; mc[u] = vr[u]; }
#pragma unroll
      for (int u = 0; u < 6; ++u) vr[u] *= occ[nm * 6 + u];
      float s2 = vr[0]+vr[1]+vr[2]+vr[3]+vr[4]+vr[5];
#pragma unroll
      for (int u = 0; u < 6; ++u) msk6[u] = ((s2 == 0.f) ? 1.f : vr[u]) * mc[u];
    } else {
#pragma unroll
      for (int u = 0; u < 6; ++u) msk6[u] = 1.f;
    }
#pragma unroll
    for (int u = 0; u < 6; ++u) addm6[u] = (msk6[u] == 0.f) ? -INFINITY : 0.f;
  }

  // ---- stage feat -> bf16 A-tile in B1 (packed b32 writes) ----
  if (lane < 24) {
    int r12 = lane >> 1, half = lane & 1;
    int s = r12 / 6, v = r12 - s * 6;
    int n = n0 + s;
    int row = s * 8 + v;
    unsigned* dst = (unsigned*)(B1 + row * 40) + half * 8;
    if (n < ntot) {
      const float* fb = feat + (size_t)(n * 6 + v) * 48;
      if (half == 0) {
        float4 fA = *(const float4*)(fb + 24);
        float4 fB = *(const float4*)(fb + 28);
        float4 fC = *(const float4*)(fb + 32);
        float4 fD = *(const float4*)(fb + 36);
        dst[0] = pk2(fb[47], fA.x); dst[1] = pk2(fA.y, fA.z);
        dst[2] = pk2(fA.w, fB.x);  dst[3] = pk2(fB.y, fB.z);
        dst[4] = pk2(fB.w, fC.x);  dst[5] = pk2(fC.y, fC.z);
        dst[6] = pk2(fC.w, fD.x);  dst[7] = pk2(fD.y, fD.z);
      } else {
        float4 fE = *(const float4*)(fb + 40);
        dst[0] = pk2(fb[39], fE.x); dst[1] = pk2(fE.y, fE.z);
        dst[2] = pk2(fE.w, 0.f);
        dst[3] = 0u; dst[4] = 0u; dst[5] = 0u; dst[6] = 0u; dst[7] = 0u;
      }
    } else {
#pragma unroll
      for (int j = 0; j < 8; ++j) dst[j] = 0u;
    }
  } else if (lane < 40) {
    int pr = (lane - 24) >> 2, q = (lane - 24) & 3;
    int row = (pr >> 1) * 8 + 6 + (pr & 1);
    unsigned* dst = (unsigned*)(B1 + row * 40) + q * 4;
    dst[0] = 0u; dst[1] = 0u; dst[2] = 0u; dst[3] = 0u;
  }
  __syncthreads();   // WTL(wtok) + B1 A-tiles ready

  // ---- token embedding: MFMA pair + ELU, paired-col store -> B0 ----
  {
    s16x8 a = *(const s16x8*)(B1 + c * 40 + (gq << 3));
    f32x4 c0 = {0.f,0.f,0.f,0.f}, c1 = c0;
    c0 = mfma16(a, ldB32(WTL, 0, c, gq), c0);
    c1 = mfma16(a, ldB32(WTL, 1, c, gq), c1);
    float2 tb = *(const float2*)(tokb + 2 * c);
#pragma unroll
    for (int i = 0; i < 4; ++i) {
      int row = gq * 4 + i;
      *(unsigned*)(B0 + row * 40 + 2 * c) = pk2(elu_f(c0[i] + tb.x), elu_f(c1[i] + tb.y));
    }
  }
  __syncthreads();   // all waves done reading WTL before layer-0 K/V overwrite it

  // ---- transformer layers: QKV' / attn+LN1 / FFN1 / LN2 ----
  for (int l = 0; l < 4; ++l) {
    const unsigned short* wl = wsq + l * 6144;

    // QKV': Q -> B1, K -> B2, V~ = T @ (Wv@Wo) -> B3
    {
      s16x8 a = *(const s16x8*)(B0 + c * 40 + (gq << 3));
      f32x4 cq0 = {0.f,0.f,0.f,0.f}, cq1 = cq0, ck0 = cq0, ck1 = cq0, cv0 = cq0, cv1 = cq0;
      cq0 = mfma16(a, ldB32(wl,        0, c, gq), cq0);
      cq1 = mfma16(a, ldB32(wl,        1, c, gq), cq1);
      ck0 = mfma16(a, ldB32(wl + 1024, 0, c, gq), ck0);
      ck1 = mfma16(a, ldB32(wl + 1024, 1, c, gq), ck1);
      cv0 = mfma16(a, ldB32(wl + 2048, 0, c, gq), cv0);
      cv1 = mfma16(a, ldB32(wl + 2048, 1, c, gq), cv1);
#pragma unroll
      for (int i = 0; i < 4; ++i) {
        int ro = (gq * 4 + i) * 40 + 2 * c;
        *(unsigned*)(B1 + ro) = pk2(cq0[i], cq1[i]);
        *(unsigned*)(B2 + ro) = pk2(ck0[i], ck1[i]);
        *(unsigned*)(B3 + ro) = pk2(cv0[i], cv1[i]);
      }
    }
    __builtin_amdgcn_wave_barrier();

    // attention + residual + LN1 (48 lane jobs (s,q,h)); X -> own Q-slot in B1.
    // h-lanes of one (s,q) form an aligned DPP quad -> quad_sum reduction.
    if (lane < 48) {
      int s = lane / 24, t = lane - s * 24, q = t >> 2, h = t & 3;
      int row = s * 8 + q;
      uint4 qf = *(const uint4*)(B1 + row * 40 + h * 8);
      float p6[6];
#pragma unroll
      for (int u = 0; u < 6; ++u) {
        uint4 kf = *(const uint4*)(B2 + (s * 8 + u) * 40 + h * 8);
        float d = dot2bf(qf.x, kf.x, 0.f);
        d = dot2bf(qf.y, kf.y, d);
        d = dot2bf(qf.z, kf.z, d);
        d = dot2bf(qf.w, kf.w, d);
        p6[u] = fmaf(d, ATTN_SCALE, addm6[u]);
      }
      float mx = p6[0];
#pragma unroll
      for (int u = 1; u < 6; ++u) mx = fmaxf(mx, p6[u]);
      float sum = 0.f;
#pragma unroll
      for (int u = 0; u < 6; ++u) { float e = __expf(p6[u] - mx); p6[u] = e; sum += e; }
      float inv = 1.f / sum;
      float o[8];
#pragma unroll
      for (int i = 0; i < 8; ++i) o[i] = 0.f;
#pragma unroll
      for (int u = 0; u < 6; ++u) {
        s16x8 vf = *(const s16x8*)(B3 + (s * 8 + u) * 40 + h * 8);
        float pw = p6[u] * inv;
#pragma unroll
        for (int i = 0; i < 8; ++i) o[i] += pw * fbc((unsigned short)vf[i]);
      }
      // + residual (token row from B0, this head's 8 cols)
      s16x8 rf = *(const s16x8*)(B0 + row * 40 + h * 8);
#pragma unroll
      for (int i = 0; i < 8; ++i) o[i] += fbc((unsigned short)rf[i]);
      // LN1 over 32 cols via quad reduction across the 4 h-lanes
      float s1 = 0.f, s2 = 0.f;
#pragma unroll
      for (int i = 0; i < 8; ++i) { s1 += o[i]; s2 += o[i] * o[i]; }
      s1 = quad_sum(s1);
      s2 = quad_sum(s2);
      float mean = s1 * 0.03125f;
      float var  = fmaxf(s2 * 0.03125f - mean * mean, 0.f);
      float rr   = rsqrtf(var + 1e-6f);
      float4 ga = *(const float4*)(ln1g + l * 32 + h * 8);
      float4 gb = *(const float4*)(ln1g + l * 32 + h * 8 + 4);
      float4 ba = *(const float4*)(ln1b + l * 32 + h * 8);
      float4 bb = *(const float4*)(ln1b + l * 32 + h * 8 + 4);
      unsigned* xp = (unsigned*)(B1 + row * 40 + h * 8);
      xp[0] = pk2((o[0] - mean) * rr * ga.x + ba.x, (o[1] - mean) * rr * ga.y + ba.y);
      xp[1] = pk2((o[2] - mean) * rr * ga.z + ba.z, (o[3] - mean) * rr * ga.w + ba.w);
      xp[2] = pk2((o[4] - mean) * rr * gb.x + bb.x, (o[5] - mean) * rr * gb.y + bb.y);
      xp[3] = pk2((o[6] - mean) * rr * gb.z + bb.z, (o[7] - mean) * rr * gb.w + bb.w);
    }
    __builtin_amdgcn_wave_barrier();

    // H = relu(X @ W1 + b1):  A=B1 -> B3 (V~ dead)
    {
      s16x8 a = *(const s16x8*)(B1 + c * 40 + (gq << 3));
      f32x4 c0 = {0.f,0.f,0.f,0.f}, c1 = c0;
      c0 = mfma16(a, ldB32(wl + 4096, 0, c, gq), c0);
      c1 = mfma16(a, ldB32(wl + 4096, 1, c, gq), c1);
      float2 bi = *(const float2*)(fb1 + l*32 + 2*c);
#pragma unroll
      for (int i = 0; i < 4; ++i) {
        int row = gq * 4 + i;
        *(unsigned*)(B3 + row * 40 + 2 * c) =
            pk2(fmaxf(c0[i] + bi.x, 0.f), fmaxf(c1[i] + bi.y, 0.f));
      }
    }
    __builtin_amdgcn_wave_barrier();

    // T' = LN2(H @ W2 + b2 + X[B1]) -> B0
    {
      s16x8 a = *(const s16x8*)(B3 + c * 40 + (gq << 3));
      f32x4 c0 = {0.f,0.f,0.f,0.f}, c1 = c0;
      c0 = mfma16(a, ldB32(wl + 5120, 0, c, gq), c0);
      c1 = mfma16(a, ldB32(wl + 5120, 1, c, gq), c1);
      float2 g2 = *(const float2*)(ln2g + l*32 + 2*c);
      float2 b2 = *(const float2*)(ln2b + l*32 + 2*c);
      float2 bi = *(const float2*)(fb2 + l*32 + 2*c);
#pragma unroll
      for (int i = 0; i < 4; ++i) {
        int row = gq * 4 + i;
        unsigned xp = *(const unsigned*)(B1 + row * 40 + 2 * c);
        float x0 = c0[i] + bi.x + f_lo(xp);
        float x1 = c1[i] + bi.y + f_hi(xp);
        float s  = row16_sum(x0 + x1);
        float ss = row16_sum(x0 * x0 + x1 * x1);
        float mean = s * 0.03125f;
        float var  = fmaxf(ss * 0.03125f - mean * mean, 0.f);
        float rr   = rsqrtf(var + 1e-6f);
        *(unsigned*)(B0 + row * 40 + 2 * c) =
            pk2((x0 - mean) * rr * g2.x + b2.x, (x1 - mean) * rr * g2.y + b2.y);
      }
    }
    __builtin_amdgcn_wave_barrier();
  }

  // ---- head: block = 16 samples = one M=16 tile ----
  __syncthreads();   // transformer done; B1/B2 regions dead -> alias e1/e2/WTL

  // stage wt3 -> WTL: WT3[n(32)][k(96)], n>=20 zero (original order)
  for (int t = tid; t < 3072; t += 512) {
    int n = t / 96, k = t - n * 96;
    WTL[t] = (n < 20) ? bfc(fc3w[k * 20 + n]) : (unsigned short)0;
  }

  // fc1: A-frag sample = c, k = (v=ck)*32.. ; 12 n-tiles over 8 waves
  // sequential store-then-compute to cap register pressure
  {
    s16x8 a6[6];
#pragma unroll
    for (int ck = 0; ck < 6; ++ck)
      a6[ck] = *(const s16x8*)(SH + (c >> 1) * WSLICE + ((c & 1) * 8 + ck) * 40 + (gq << 3));
    int nt = wid;
    f32x4 acc = {0.f,0.f,0.f,0.f};
#pragma unroll
    for (int ck = 0; ck < 6; ++ck)
      acc = mfma16(a6[ck], *(const s16x8*)(wt1 + (nt*16 + c) * 192 + ck*32 + (gq << 3)), acc);
    float bi = fc1b[nt * 16 + c];
#pragma unroll
    for (int i = 0; i < 4; ++i)
      e1[(gq * 4 + i) * 200 + nt * 16 + c] = bfc(elu_f(acc[i] + bi));
    if (wid < 4) {
      int nt2 = wid + 8;
      f32x4 acc2 = {0.f,0.f,0.f,0.f};
#pragma unroll
      for (int ck = 0; ck < 6; ++ck)
        acc2 = mfma16(a6[ck], *(const s16x8*)(wt1 + (nt2*16 + c) * 192 + ck*32 + (gq << 3)), acc2);
      float bi2 = fc1b[nt2 * 16 + c];
#pragma unroll
      for (int i = 0; i < 4; ++i)
        e1[(gq * 4 + i) * 200 + nt2 * 16 + c] = bfc(elu_f(acc2[i] + bi2));
    }
  }
  __syncthreads();

  // fc2: 6 n-tiles over waves 0..5
  if (wid < 6) {
    s16x8 h6[6];
#pragma unroll
    for (int ck = 0; ck < 6; ++ck)
      h6[ck] = *(const s16x8*)(e1 + c * 200 + ck * 32 + (gq << 3));
    int nt = wid;
    f32x4 acc = {0.f,0.f,0.f,0.f};
#pragma unroll
    for (int ck = 0; ck < 6; ++ck)
      acc = mfma16(h6[ck], *(const s16x8*)(wt2 + (nt*16 + c) * 192 + ck*32 + (gq << 3)), acc);
    float bi = fc2b[nt * 16 + c];
    int base = nt * 16 + c;
#pragma unroll
    for (int i = 0; i < 4; ++i)
      e2[(gq * 4 + i) * 104 + base] = bfc(elu_f(acc[i] + bi));
  }
  __syncthreads();

  // fc3: M=16 x N=20(pad32) x K=96 on waves 6,7 (3 MFMAs each)
  if (wid >= 6) {
    int nt = wid - 6;
    s16x8 a3[3];
#pragma unroll
    for (int ck = 0; ck < 3; ++ck)
      a3[ck] = *(const s16x8*)(e2 + c * 104 + ck * 32 + (gq << 3));
    f32x4 acc = {0.f,0.f,0.f,0.f};
#pragma unroll
    for (int ck = 0; ck < 3; ++ck)
      acc = mfma16(a3[ck], *(const s16x8*)(WTL + (nt*16 + c) * 96 + ck*32 + (gq << 3)), acc);
    int col = nt * 16 + c;
    if (col < 20) {
      float bi = fc3b[col];
#pragma unroll
      for (int i = 0; i < 4; ++i) {
        int n = n0b + gq * 4 + i;
        if (n < ntot) outp[(size_t)n * 20 + col] = fmaxf(acc[i] + bi, 0.f);
      }
    }
  }
}

extern "C" void kernel_launch(void* const* d_in, const int* in_sizes, int n_in,
                              void* d_out, int out_size, void* d_ws, size_t ws_size,
                              hipStream_t stream)
{
  const float* feat = (const float*)d_in[0];
  const float* occ  = (const float*)d_in[1];
  const float* tokw = (const float*)d_in[2];
  const float* tokb = (const float*)d_in[3];
  const float* wq   = (const float*)d_in[4];
  const float* wk   = (const float*)d_in[5];
  const float* wv   = (const float*)d_in[6];
  const float* wo   = (const float*)d_in[7];
  const float* ln1g = (const float*)d_in[8];
  const float* ln1b = (const float*)d_in[9];
  const float* fw1  = (const float*)d_in[10];
  const float* fb1  = (const float*)d_in[11];
  const float* fw2  = (const float*)d_in[12];
  const float* fb2  = (const float*)d_in[13];
  const float* ln2g = (const float*)d_in[14];
  const float* ln2b = (const float*)d_in[15];
  const float* fc1w = (const float*)d_in[16];
  const float* fc1b = (const float*)d_in[17];
  const float* fc2w = (const float*)d_in[18];
  const float* fc2b = (const float*)d_in[19];
  const float* fc3w = (const float*)d_in[20];
  const float* fc3b = (const float*)d_in[21];
  float* outp = (float*)d_out;

  unsigned short* ws = (unsigned short*)d_ws;
  const int ntot = in_sizes[0] / 288;

  hipLaunchKernelGGL(prep_kernel, dim3(128), dim3(256), 0, stream,
                     wq, wk, wv, wo, fw1, fw2, fc1w, fc2w, ws);

  const int grid = (ntot + 15) / 16;
  hipLaunchKernelGGL(sem_main, dim3(grid), dim3(512), 0, stream,
                     feat, occ, tokw, tokb, ln1g, ln1b, fb1, fb2, ln2g, ln2b,
                     fc1b, fc2b, fc3w, fc3b,
                     ws, ws + 24576, ws + 61440,
                     outp, ntot);
}